// Round 1
// baseline (298.645 us; speedup 1.0000x reference)
//
#include <hip/hip_runtime.h>

#define S_ 256
#define D_ 128
#define K_ 26

__global__ __launch_bounds__(64, 1) void viterbi_fused(
    const float* __restrict__ X,    // [B,S,D]
    const float* __restrict__ W,    // [K,D]
    const float* __restrict__ Tr,   // [K,K]
    int* __restrict__ out)          // [B,S] int32
{
  const int b    = blockIdx.x;
  const int lane = threadIdx.x;
  const int j    = lane & 31;   // state (valid < 26)
  const int h    = lane >> 5;   // D-half
  const int jc   = (j < K_) ? j : 0;

  __shared__ unsigned char bp[S_][32];  // backptrs, t = 1..255
  __shared__ int path_s[S_];

  // per-lane W fragment: w[d] = W[jc][h*64 + d]
  float w[64];
  {
    const float4* wp = reinterpret_cast<const float4*>(W + jc * D_ + h * 64);
#pragma unroll
    for (int q = 0; q < 16; ++q) {
      float4 v = wp[q];
      w[4*q+0] = v.x; w[4*q+1] = v.y; w[4*q+2] = v.z; w[4*q+3] = v.w;
    }
  }
  // transition column: tc[i] = Tr[i][jc]
  float tc[K_];
#pragma unroll
  for (int i = 0; i < K_; ++i) tc[i] = Tr[i * K_ + jc];

  const float* xbase = X + (size_t)b * (S_ * D_) + h * 64;

  float4 xA[16], xB[16];

  auto issue = [&](float4 (&dst)[16], int t) {
    const float4* xp = reinterpret_cast<const float4*>(xbase + (size_t)t * D_);
#pragma unroll
    for (int q = 0; q < 16; ++q) dst[q] = xp[q];
  };
  auto dot64 = [&](const float4 (&src)[16]) -> float {
    float a0 = 0.f, a1 = 0.f, a2 = 0.f, a3 = 0.f;
#pragma unroll
    for (int q = 0; q < 16; ++q) {
      a0 = fmaf(src[q].x, w[4*q+0], a0);
      a1 = fmaf(src[q].y, w[4*q+1], a1);
      a2 = fmaf(src[q].z, w[4*q+2], a2);
      a3 = fmaf(src[q].w, w[4*q+3], a3);
    }
    float p = (a0 + a1) + (a2 + a3);
    return p + __shfl_xor(p, 32, 64);  // combine the two D-halves
  };

  auto trans = [&](float dlt, float e, int t) -> float {
    float best = __shfl(dlt, 0, 64) + tc[0];
    int bpi = 0;
#pragma unroll
    for (int i = 1; i < K_; ++i) {
      float s = __shfl(dlt, i, 64) + tc[i];
      bool g = s > best;          // strict > keeps FIRST max (jnp.argmax)
      best = g ? s : best;
      bpi  = g ? i : bpi;
    }
    if (h == 0) bp[t][j] = (unsigned char)bpi;
    return best + e;
  };

  float delta;
  { // t = 0: delta0 = emis[:,0,:]
    issue(xA, 0);
    delta = dot64(xA);
  }
  issue(xA, 1);
  issue(xB, 2);

  for (int t = 1; t <= S_ - 3; t += 2) {   // t = 1,3,...,253
    float e0 = dot64(xA);                  // x_t
    issue(xA, (t + 2 <= S_ - 1) ? t + 2 : S_ - 1);
    delta = trans(delta, e0, t);
    float e1 = dot64(xB);                  // x_{t+1}
    issue(xB, (t + 3 <= S_ - 1) ? t + 3 : S_ - 1);
    delta = trans(delta, e1, t + 1);
  }
  { // t = 255
    float e0 = dot64(xA);
    delta = trans(delta, e0, S_ - 1);
  }

  // final argmax over deltaT (first max)
  float bestf = __shfl(delta, 0, 64);
  int last = 0;
#pragma unroll
  for (int i = 1; i < K_; ++i) {
    float s = __shfl(delta, i, 64);
    bool g = s > bestf;
    bestf = g ? s : bestf;
    last  = g ? i : last;
  }

  __syncthreads();

  // backtrack: uniform across lanes (broadcast LDS reads); lane 0 records
  int cur = last;
  if (lane == 0) path_s[S_ - 1] = cur;
  for (int t = S_ - 1; t >= 1; --t) {
    cur = (int)bp[t][cur];
    if (lane == 0) path_s[t - 1] = cur;
  }
  __syncthreads();

  // coalesced path store
  int* o = out + (size_t)b * S_;
#pragma unroll
  for (int q = 0; q < 4; ++q) o[q * 64 + lane] = path_s[q * 64 + lane];
}

extern "C" void kernel_launch(void* const* d_in, const int* in_sizes, int n_in,
                              void* d_out, int out_size, void* d_ws, size_t ws_size,
                              hipStream_t stream) {
  (void)in_sizes; (void)n_in; (void)d_ws; (void)ws_size; (void)out_size;
  const float* X  = (const float*)d_in[0];
  const float* W  = (const float*)d_in[1];
  const float* Tr = (const float*)d_in[2];
  int* out = (int*)d_out;
  viterbi_fused<<<1024, 64, 0, stream>>>(X, W, Tr, out);
}